// Round 7
// baseline (42.954 us; speedup 1.0000x reference)
//
#include <hip/hip_runtime.h>

#define H 512
#define W 512

// Full-wave (64-lane) sum using DPP only — pure VALU, no DS-pipe traffic.
// After the 6 steps the total is in lane 63. (HW-verified R4-R6.)
__device__ __forceinline__ float wave_sum_dpp(float x) {
#define DPP_STEP(ctrl)                                                          \
    x += __int_as_float(__builtin_amdgcn_update_dpp(                            \
        0, __float_as_int(x), (ctrl), 0xF, 0xF, true))
    DPP_STEP(0x111);   // row_shr:1
    DPP_STEP(0x112);   // row_shr:2
    DPP_STEP(0x114);   // row_shr:4
    DPP_STEP(0x118);   // row_shr:8   -> lane15 of each row16 holds row sum
    DPP_STEP(0x142);   // row_bcast:15
    DPP_STEP(0x143);   // row_bcast:31 -> lane63 holds full wave sum
#undef DPP_STEP
    return x;
}

__device__ __forceinline__ float4 ld4(const float* p) {
    return *reinterpret_cast<const float4*>(p);
}
__device__ __forceinline__ float2 ld2(const float* p) {
    return *reinterpret_cast<const float2*>(p);
}

// Kernel 1: register-resident row-quad kernel. One wave owns 4 full image rows
// (64 lanes x 8 px = 512 = W). Target rows flow through a 4-slot register
// pipeline, depth-3 in flight, with sched_barrier(0) pins so the compiler
// CANNOT sink the loads to just-in-time (R6 failure mode: VGPR stayed 64 and
// the prefetch was rematerialized away). Halos are float2 direct loads
// (8B-aligned, wrap-safe) — no __shfl in the hot path.
__global__ __launch_bounds__(256, 4)
void dice_partial(const float* __restrict__ in, const float* __restrict__ tg,
                  float* __restrict__ ws, int nblocks) {
    __shared__ float warr[4][32];   // [wave][quantity 0..26]

    const int tid  = threadIdx.x;
    const int wave = tid >> 6, lane = tid & 63;

    // Bijective XCD chunking (nblocks % 8 == 0).
    const int bid = blockIdx.x;
    const int wrk = (bid & 7) * (nblocks >> 3) + (bid >> 3);

    const int q  = wrk * 4 + wave;        // global row-quad id
    const int b  = q >> 7;                // batch (128 quads per image)
    const int y0 = (q & 127) << 2;        // first of 4 owned rows (<= 508)
    const float* __restrict__ ib = in + (size_t)b * (H * W);
    const float* __restrict__ tb = tg + (size_t)b * (H * W);

    const int c0 = lane * 8;              // my 8 columns: c0..c0+7
    const int cl = (c0 - 2) & (W - 1);    // left halo float2 (cols c0-2,c0-1), 8B aligned
    const int cr = (c0 + 8) & (W - 1);    // right halo float2 (cols c0+8,c0+9)

    // ---- issue the 8 input-row loads (oldest in the vmem queue) ----
    float4 ia[4], ic[4];
#pragma unroll
    for (int yi = 0; yi < 4; ++yi) {
        const float* rp = ib + (size_t)(y0 + yi) * W;   // y0+3 <= 511, no wrap
        ia[yi] = ld4(rp + c0);
        ic[yi] = ld4(rp + c0 + 4);
    }

    // ---- 4-slot target-row pipeline: row t -> b128,b128,b64,b64 ----
    float4 ta[4], tc[4];
    float2 tl[4], tr[4];
#define TROW(t) (tb + (size_t)((y0 - 2 + (t)) & (H - 1)) * W)
#define ISSUE(slot, t) {                                        \
        const float* tp = TROW(t);                              \
        ta[slot] = ld4(tp + c0);                                \
        tc[slot] = ld4(tp + c0 + 4);                            \
        tl[slot] = ld2(tp + cl);                                \
        tr[slot] = ld2(tp + cr); }

    ISSUE(0, 0)
    ISSUE(1, 1)
    ISSUE(2, 2)
    __builtin_amdgcn_sched_barrier(0);   // pin: rows 0-2 + inputs issued, period.

    // ---- unpack input rows (waits inputs; 12 target loads stay outstanding) ----
    float iv[4][8];
    float isum = 0.f;
#pragma unroll
    for (int yi = 0; yi < 4; ++yi) {
        iv[yi][0] = ia[yi].x; iv[yi][1] = ia[yi].y;
        iv[yi][2] = ia[yi].z; iv[yi][3] = ia[yi].w;
        iv[yi][4] = ic[yi].x; iv[yi][5] = ic[yi].y;
        iv[yi][6] = ic[yi].z; iv[yi][7] = ic[yi].w;
#pragma unroll
        for (int j = 0; j < 8; ++j) isum += iv[yi][j];
    }

    float acc[25];
#pragma unroll
    for (int k = 0; k < 25; ++k) acc[k] = 0.f;
    float tsum = 0.f;

    // ---- 8 target rows (y0-2 .. y0+5); issue t+3 BEFORE consuming t ----
#pragma unroll
    for (int t = 0; t < 8; ++t) {
        if (t + 3 < 8) {
            ISSUE((t + 3) & 3, t + 3)              // slot (t+3)&3 != t&3
            __builtin_amdgcn_sched_barrier(0);     // pin: no sinking below
        }

        const int s = t & 3;                       // compile-time under unroll
        float tw[12];                              // tw[c] = target col c0 + c - 2
        tw[0]  = tl[s].x; tw[1]  = tl[s].y;
        tw[2]  = ta[s].x; tw[3]  = ta[s].y; tw[4] = ta[s].z; tw[5] = ta[s].w;
        tw[6]  = tc[s].x; tw[7]  = tc[s].y; tw[8] = tc[s].z; tw[9] = tc[s].w;
        tw[10] = tr[s].x; tw[11] = tr[s].y;

        if (t >= 2 && t <= 5) {                    // rows y0..y0+3: count each tg elem once
#pragma unroll
            for (int j = 0; j < 8; ++j) tsum += tw[j + 2];
        }

#pragma unroll
        for (int yi = 0; yi < 4; ++yi) {
            const int sy = yi + 2 - t;             // roll shift pairing
            if (sy < -2 || sy > 2) continue;       // compile-time prune (20 live pairs)
#pragma unroll
            for (int sx = -2; sx <= 2; ++sx) {
#pragma unroll
                for (int j = 0; j < 8; ++j)
                    acc[(sy + 2) * 5 + (sx + 2)] += iv[yi][j] * tw[j + 2 - sx];
            }
        }
    }
#undef ISSUE
#undef TROW

    // ---- per-wave DPP reduction of 27 quantities, then per-block combine ----
#pragma unroll
    for (int k = 0; k < 25; ++k) {
        const float v = wave_sum_dpp(acc[k]);
        if (lane == 63) warr[wave][k] = v;
    }
    {
        const float v = wave_sum_dpp(isum);
        if (lane == 63) warr[wave][25] = v;
        const float u = wave_sum_dpp(tsum);
        if (lane == 63) warr[wave][26] = u;
    }

    __syncthreads();
    if (tid < 27) {
        const float s = warr[0][tid] + warr[1][tid] + warr[2][tid] + warr[3][tid];
        ws[tid * nblocks + bid] = s;   // [k][block] layout for coalesced pass 2
    }
}

// Kernel 2: 27 blocks, block k tree-reduces the per-block partials for quantity k.
__global__ __launch_bounds__(256)
void dice_reduce(const float* __restrict__ ws, float* __restrict__ tot, int nblocks) {
    __shared__ float red[4];
    const int k = blockIdx.x;
    const int tid = threadIdx.x;
    const float* p = ws + (size_t)k * nblocks;

    float s = 0.f;
    for (int i = tid; i < nblocks; i += 256) s += p[i];
    s = wave_sum_dpp(s);
    if ((tid & 63) == 63) red[tid >> 6] = s;
    __syncthreads();
    if (tid == 0) tot[k] = red[0] + red[1] + red[2] + red[3];
}

// Kernel 3: one wave — 25-way max + final loss scalar.
__global__ void dice_out(const float* __restrict__ tot, float* __restrict__ out) {
    const int tid = threadIdx.x;   // blockDim = 64
    float v = (tid < 25) ? tot[tid] : -1e30f;
#pragma unroll
    for (int off = 32; off; off >>= 1) v = fmaxf(v, __shfl_down(v, off, 64));
    if (tid == 0) {
        const float denom = tot[25] + tot[26] + 1.0f;   // i_sum + t_sum + SMOOTH
        out[0] = 1.0f - (2.0f * v + 1.0f) / denom;      // min loss == max intersection
    }
}

extern "C" void kernel_launch(void* const* d_in, const int* in_sizes, int n_in,
                              void* d_out, int out_size, void* d_ws, size_t ws_size,
                              hipStream_t stream) {
    const float* inputs  = (const float*)d_in[0];
    const float* targets = (const float*)d_in[1];
    float* out = (float*)d_out;
    float* ws  = (float*)d_ws;

    const int B = in_sizes[0] / (H * W);    // 64
    const int nblocks = B * (H / 4) / 4;    // 2048 blocks x 4 waves x 4 rows

    float* tot = ws + (size_t)27 * nblocks; // 27 scalar totals after the partial table

    dice_partial<<<nblocks, 256, 0, stream>>>(inputs, targets, ws, nblocks);
    dice_reduce<<<27, 256, 0, stream>>>(ws, tot, nblocks);
    dice_out<<<1, 64, 0, stream>>>(tot, out);
}

// Round 8
// 38.762 us; speedup vs baseline: 1.1081x; 1.1081x over previous
//
#include <hip/hip_runtime.h>

#define H 512
#define W 512
#define RROWS 32            // rows per block (8 waves x 4 rows)
#define TGR  (RROWS + 4)    // staged target rows incl. +-2 halo = 36
#define NCHUNK (TGR * 2)    // 72 chunks of 256 floats (1 KB DMA each)

// Full-wave (64-lane) sum using DPP only — pure VALU. Result in lane 63.
__device__ __forceinline__ float wave_sum_dpp(float x) {
#define DPP_STEP(ctrl)                                                          \
    x += __int_as_float(__builtin_amdgcn_update_dpp(                            \
        0, __float_as_int(x), (ctrl), 0xF, 0xF, true))
    DPP_STEP(0x111);   // row_shr:1
    DPP_STEP(0x112);   // row_shr:2
    DPP_STEP(0x114);   // row_shr:4
    DPP_STEP(0x118);   // row_shr:8
    DPP_STEP(0x142);   // row_bcast:15
    DPP_STEP(0x143);   // row_bcast:31
#undef DPP_STEP
    return x;
}

__device__ __forceinline__ float4 ld4(const float* p) {
    return *reinterpret_cast<const float4*>(p);
}
__device__ __forceinline__ float2 ld2(const float* p) {
    return *reinterpret_cast<const float2*>(p);
}

// Async global->LDS DMA, 16 B per lane (lds dest = base + lane*16, linear).
__device__ __forceinline__ void gl_lds16(const float* g, float* l) {
    __builtin_amdgcn_global_load_lds(
        (const __attribute__((address_space(1))) void*)g,
        (__attribute__((address_space(3))) void*)l,
        16, 0, 0);
}

// Kernel 1: 512-thread block owns a 32x512 slab. Inputs -> registers (4 rows
// per wave). Target rows (36 incl. halo) -> LDS via global_load_lds: the DMA
// queue, not VGPRs, holds in-flight data (R5-R7 failure mode: compiler refuses
// to keep a register prefetch pipeline live; VGPR pinned at 64). Column halo
// read directly from LDS with in-row wrap; zero cross-lane ops in hot path.
__global__ __launch_bounds__(512, 4)
void dice_partial(const float* __restrict__ in, const float* __restrict__ tg,
                  float* __restrict__ ws, int nblocks) {
    __shared__ __align__(16) float tgs[TGR * W];   // 73728 B, linear
    __shared__ float warr[8][32];                  // [wave][quantity 0..26]

    const int tid  = threadIdx.x;
    const int wave = tid >> 6, lane = tid & 63;

    // Bijective XCD chunking (nblocks % 8 == 0); consecutive slabs share halo.
    const int bid = blockIdx.x;
    const int wrk = (bid & 7) * (nblocks >> 3) + (bid >> 3);

    const int b  = wrk >> 4;              // image (16 slabs per image)
    const int y0 = (wrk & 15) * RROWS;    // slab top row
    const float* __restrict__ ib = in + (size_t)b * (H * W);
    const float* __restrict__ tb = tg + (size_t)b * (H * W);

    const int c0 = lane * 8;              // my 8 columns

    // ---- issue 8 input-row loads first (oldest in vmcnt queue) ----
    const int ry = y0 + wave * 4;         // this wave's first input row (<=508)
    float4 ia[4], ic[4];
#pragma unroll
    for (int yi = 0; yi < 4; ++yi) {
        const float* rp = ib + (size_t)(ry + yi) * W;
        ia[yi] = ld4(rp + c0);
        ic[yi] = ld4(rp + c0 + 4);
    }

    // ---- issue 9 DMA chunks per wave: target rows y0-2 .. y0+33 ----
#pragma unroll
    for (int k = 0; k < 9; ++k) {
        const int c    = wave * 9 + k;          // chunk id, wave-uniform
        const int rr   = c >> 1;                // staged row index
        const int half = (c & 1) * 256;         // half-row offset (floats)
        const int ra   = (y0 - 2 + rr) & (H - 1);
        gl_lds16(tb + (size_t)ra * W + half + lane * 4, &tgs[c * 256]);
    }

    // ---- unpack inputs + isum (VALU work overlapping the DMA fill) ----
    float iv[4][8];
    float isum = 0.f;
#pragma unroll
    for (int yi = 0; yi < 4; ++yi) {
        iv[yi][0] = ia[yi].x; iv[yi][1] = ia[yi].y;
        iv[yi][2] = ia[yi].z; iv[yi][3] = ia[yi].w;
        iv[yi][4] = ic[yi].x; iv[yi][5] = ic[yi].y;
        iv[yi][6] = ic[yi].z; iv[yi][7] = ic[yi].w;
#pragma unroll
        for (int j = 0; j < 8; ++j) isum += iv[yi][j];
    }
    isum = wave_sum_dpp(isum);
    if (lane == 63) warr[wave][25] = isum;

    __syncthreads();   // drains vmcnt(0): all DMA chunks landed

    float acc[25];
#pragma unroll
    for (int k = 0; k < 25; ++k) acc[k] = 0.f;
    float tsum = 0.f;

    // ---- 8 target rows per wave from LDS (rr = 4*wave + t) ----
#pragma unroll
    for (int t = 0; t < 8; ++t) {
        const float* rowp = &tgs[(wave * 4 + t) * W];
        float tw[12];                      // tw[c] = target col c0 + c - 2
        const float4 a  = ld4(rowp + c0);
        const float4 cc = ld4(rowp + c0 + 4);
        const float2 lf = ld2(rowp + ((c0 - 2) & (W - 1)));
        const float2 rg = ld2(rowp + ((c0 + 8) & (W - 1)));
        tw[0]  = lf.x; tw[1]  = lf.y;
        tw[2]  = a.x;  tw[3]  = a.y;  tw[4] = a.z;  tw[5] = a.w;
        tw[6]  = cc.x; tw[7]  = cc.y; tw[8] = cc.z; tw[9] = cc.w;
        tw[10] = rg.x; tw[11] = rg.y;

        if (t >= 2 && t <= 5) {            // rows ry..ry+3: count each tg elem once
#pragma unroll
            for (int j = 0; j < 8; ++j) tsum += tw[j + 2];
        }

#pragma unroll
        for (int yi = 0; yi < 4; ++yi) {
            const int sy = yi + 2 - t;     // roll shift pairing
            if (sy < -2 || sy > 2) continue;   // compile-time prune (20 live pairs)
#pragma unroll
            for (int sx = -2; sx <= 2; ++sx) {
#pragma unroll
                for (int j = 0; j < 8; ++j)
                    acc[(sy + 2) * 5 + (sx + 2)] += iv[yi][j] * tw[j + 2 - sx];
            }
        }
    }

    // ---- per-wave DPP reduction of 26 remaining quantities ----
#pragma unroll
    for (int k = 0; k < 25; ++k) {
        const float v = wave_sum_dpp(acc[k]);
        if (lane == 63) warr[wave][k] = v;
    }
    {
        const float u = wave_sum_dpp(tsum);
        if (lane == 63) warr[wave][26] = u;
    }

    __syncthreads();
    if (tid < 27) {
        float s = 0.f;
#pragma unroll
        for (int w = 0; w < 8; ++w) s += warr[w][tid];
        ws[tid * nblocks + bid] = s;   // [k][block] layout for coalesced pass 2
    }
}

// Kernel 2: 27 blocks, block k tree-reduces the per-block partials for quantity k.
__global__ __launch_bounds__(256)
void dice_reduce(const float* __restrict__ ws, float* __restrict__ tot, int nblocks) {
    __shared__ float red[4];
    const int k = blockIdx.x;
    const int tid = threadIdx.x;
    const float* p = ws + (size_t)k * nblocks;

    float s = 0.f;
    for (int i = tid; i < nblocks; i += 256) s += p[i];
    s = wave_sum_dpp(s);
    if ((tid & 63) == 63) red[tid >> 6] = s;
    __syncthreads();
    if (tid == 0) tot[k] = red[0] + red[1] + red[2] + red[3];
}

// Kernel 3: one wave — 25-way max + final loss scalar.
__global__ void dice_out(const float* __restrict__ tot, float* __restrict__ out) {
    const int tid = threadIdx.x;   // blockDim = 64
    float v = (tid < 25) ? tot[tid] : -1e30f;
#pragma unroll
    for (int off = 32; off; off >>= 1) v = fmaxf(v, __shfl_down(v, off, 64));
    if (tid == 0) {
        const float denom = tot[25] + tot[26] + 1.0f;   // i_sum + t_sum + SMOOTH
        out[0] = 1.0f - (2.0f * v + 1.0f) / denom;      // min loss == max intersection
    }
}

extern "C" void kernel_launch(void* const* d_in, const int* in_sizes, int n_in,
                              void* d_out, int out_size, void* d_ws, size_t ws_size,
                              hipStream_t stream) {
    const float* inputs  = (const float*)d_in[0];
    const float* targets = (const float*)d_in[1];
    float* out = (float*)d_out;
    float* ws  = (float*)d_ws;

    const int B = in_sizes[0] / (H * W);    // 64
    const int nblocks = B * (H / RROWS);    // 64 x 16 = 1024 slabs

    float* tot = ws + (size_t)27 * nblocks; // 27 scalar totals after the partial table

    dice_partial<<<nblocks, 512, 0, stream>>>(inputs, targets, ws, nblocks);
    dice_reduce<<<27, 256, 0, stream>>>(ws, tot, nblocks);
    dice_out<<<1, 64, 0, stream>>>(tot, out);
}